// Round 5
// baseline (142.704 us; speedup 1.0000x reference)
//
#include <hip/hip_runtime.h>
#include <hip/hip_bf16.h>

// B=4, C=128, H=W=64 -> N=4096. ALL I/O FP32.
// Round 10: occupancy + kernel-count attack.
//  - flash: 48KB LDS (K single 16KB + V dbuf 32KB) -> 3 blocks/CU; SPLIT=6
//    (768 blocks = exactly 3/CU, uneven chunks 11x4+10x2). New schedule:
//    B1(K/V landed) -> QK^T -> B1.5(K readers done) -> issue K(t+1),V(t+1)
//    DMA -> softmax -> PV -> loop (vmcnt(0) at top has softmax+PV slack).
//    K LDS base now compile-time -> QK^T addresses loop-invariant (LICM).
//    launch_bounds stays (256,2): R8's (256,3) forced 84 VGPR -> spills.
//    No setprio (R9: +2.7us harm in lockstep structure).
//  - proj: W converted in-register from fp32 via v_cvt_pk_bf16_f32 ->
//    convert_w kernel eliminated (5 kernels -> 4, ~10us launch overhead each).

#define BATCH 4
#define CH    128
#define NTOK  4096
#define TK    64
#define TILES (NTOK / TK)
#define SCALE 0.08838834764831845f   // 1/sqrt(128)
#define LOG2E 1.4426950408889634f
#define MFIX  16.0f                  // fixed softmax offset (log2 units)

typedef __attribute__((ext_vector_type(8)))  short short8;
typedef __attribute__((ext_vector_type(4)))  float f32x4;
typedef __attribute__((ext_vector_type(16))) float f32x16;

static __device__ __forceinline__ unsigned short f2bf(float f) {
    __hip_bfloat16 h = (__hip_bfloat16)f;
    return *(const unsigned short*)&h;
}

static __device__ __forceinline__ unsigned cvt_pk_bf16(float lo, float hi) {
    unsigned r;
    asm("v_cvt_pk_bf16_f32 %0, %1, %2" : "=v"(r) : "v"(lo), "v"(hi));
    return r;
}

static __device__ __forceinline__ short8 pack_bf16x8(float4 a, float4 b) {
    union { unsigned u[4]; short8 s8; } f;
    f.u[0] = cvt_pk_bf16(a.x, a.y);
    f.u[1] = cvt_pk_bf16(a.z, a.w);
    f.u[2] = cvt_pk_bf16(b.x, b.y);
    f.u[3] = cvt_pk_bf16(b.z, b.w);
    return f.s8;
}

// ---------------- MFMA QKV projection, z-split, fused W-convert ------------
// grid (NTOK/64, BATCH, 3). W read as fp32, fragments packed to bf16 in-reg.
// Output staged in padded LDS then stored as coalesced dwordx4.
__global__ __launch_bounds__(256) void proj_mfma_kernel(
    const float* __restrict__ x,
    const float* __restrict__ Wq, const float* __restrict__ Wk,
    const float* __restrict__ Wv,
    const float* __restrict__ bq, const float* __restrict__ bk,
    const float* __restrict__ bv,
    unsigned short* __restrict__ q_ws, unsigned short* __restrict__ k_ws,
    unsigned short* __restrict__ vt_ws)
{
    __shared__ __align__(16) unsigned short XsT[64 * CH];  // 16 KB, swizzled
    __shared__ __align__(16) unsigned short Ep[128 * 72];  // 18 KB bounce

    const int t    = threadIdx.x;
    const int w    = t >> 6;
    const int lane = t & 63;
    const int quad = lane >> 4;
    const int c16  = lane & 15;
    const int n0   = blockIdx.x * 64;
    const int b    = blockIdx.y;
    const int z    = blockIdx.z;          // 0=Q, 1=K, 2=V
    const float* xb = x + (size_t)b * CH * NTOK;

    {   // stage x tile transposed: wave w covers channels 32w..32w+31
        const int tok = lane;
        #pragma unroll
        for (int cc = 0; cc < 4; ++cc) {
            const int cb = 32 * w + 8 * cc;
            unsigned short tmp[8];
            #pragma unroll
            for (int j = 0; j < 8; ++j)
                tmp[j] = f2bf(xb[(size_t)(cb + j) * NTOK + n0 + tok]);
            const int phys = ((cb >> 3) ^ (tok & 15));
            *(short8*)&XsT[tok * CH + phys * 8] = *(const short8*)tmp;
        }
    }
    __syncthreads();

    if (z < 2) {
        // ---- Q or K: out[n][c'] ; bounce via Ep[tok][136] (pad 8) ----
        const float* wm = (z == 0) ? Wq : Wk;
        const float* bias = (z == 0) ? bq : bk;
        unsigned short* dst = (z == 0) ? q_ws : k_ws;
        const float mul = (z == 0) ? (SCALE * LOG2E) : 1.0f;

        short8 xa[4];
        #pragma unroll
        for (int ks = 0; ks < 4; ++ks)
            xa[ks] = *(const short8*)&XsT[(16 * w + c16) * CH + (((4 * ks + quad) ^ c16) << 3)];

        #pragma unroll
        for (int nt = 0; nt < 8; ++nt) {
            f32x4 a = (f32x4){0.f, 0.f, 0.f, 0.f};
            const float* wr = wm + (16 * nt + c16) * CH;
            #pragma unroll
            for (int ks = 0; ks < 4; ++ks) {
                const float* wp = wr + 32 * ks + 8 * quad;
                const float4 w0 = *(const float4*)wp;
                const float4 w1 = *(const float4*)(wp + 4);
                const short8 bf = pack_bf16x8(w0, w1);
                a = __builtin_amdgcn_mfma_f32_16x16x32_bf16(xa[ks], bf, a, 0, 0, 0);
            }
            const float bvv = bias[16 * nt + c16];
            #pragma unroll
            for (int r = 0; r < 4; ++r) {
                const int tok = 16 * w + quad * 4 + r;
                Ep[tok * 136 + 16 * nt + c16] = f2bf((a[r] + bvv) * mul);
            }
        }
        __syncthreads();
        // coalesced copy-out: 4 passes x 16B/lane
        #pragma unroll
        for (int p = 0; p < 4; ++p) {
            const int tok = p * 16 + (t >> 4);
            const int u   = t & 15;
            const uint4 v = *(const uint4*)&Ep[tok * 136 + u * 8];
            *(uint4*)&dst[((size_t)b * NTOK + n0 + tok) * CH + u * 8] = v;
        }
    } else {
        // ---- V transposed: vt[c][n] ; bounce via Ep[c][72] (pad 8) ----
        short8 wva[2][4];
        float  bvv[2][4];
        #pragma unroll
        for (int mt = 0; mt < 2; ++mt) {
            const int crow16 = 16 * (2 * w + mt);
            #pragma unroll
            for (int ks = 0; ks < 4; ++ks) {
                const float* wp = Wv + (crow16 + c16) * CH + 32 * ks + 8 * quad;
                const float4 w0 = *(const float4*)wp;
                const float4 w1 = *(const float4*)(wp + 4);
                wva[mt][ks] = pack_bf16x8(w0, w1);
            }
            #pragma unroll
            for (int r = 0; r < 4; ++r)
                bvv[mt][r] = bv[crow16 + quad * 4 + r];
        }
        #pragma unroll
        for (int nt = 0; nt < 4; ++nt) {
            short8 xbf[4];
            #pragma unroll
            for (int ks = 0; ks < 4; ++ks)
                xbf[ks] = *(const short8*)&XsT[(16 * nt + c16) * CH + (((4 * ks + quad) ^ c16) << 3)];
            #pragma unroll
            for (int mt = 0; mt < 2; ++mt) {
                f32x4 acc = (f32x4){0.f, 0.f, 0.f, 0.f};
                #pragma unroll
                for (int ks = 0; ks < 4; ++ks)
                    acc = __builtin_amdgcn_mfma_f32_16x16x32_bf16(wva[mt][ks], xbf[ks], acc, 0, 0, 0);
                #pragma unroll
                for (int r = 0; r < 4; ++r) {
                    const int crow = 16 * (2 * w + mt) + quad * 4 + r;
                    Ep[crow * 72 + 16 * nt + c16] = f2bf(acc[r] + bvv[mt][r]);
                }
            }
        }
        __syncthreads();
        // coalesced copy-out: 4 passes x 16B/lane (8 lanes = one 64-tok row)
        #pragma unroll
        for (int p = 0; p < 4; ++p) {
            const int c = p * 32 + (t >> 3);
            const int u = t & 7;
            const uint4 v = *(const uint4*)&Ep[c * 72 + u * 8];
            *(uint4*)&vt_ws[((size_t)b * CH + c) * NTOK + n0 + u * 8] = v;
        }
    }
}

// ---------------- split-KV MFMA flash attention, 48KB LDS ------------------
// 4 waves x 32 q-rows. K single-buffered (16KB), V double-buffered (32KB),
// both via global_load_lds. Schedule per tile:
//   vmcnt(0); B1 [K(t),V(t) landed everywhere] -> QK^T (reads K) ->
//   B1.5 [all K readers done] -> issue K(t+1),V(t+1) DMA ->
//   softmax -> PV (reads V[cur]) -> loop.
// DMAs get softmax+PV (~1500cy) of slack before next vmcnt(0).
template <int SPLIT>
__global__ __launch_bounds__(256, 2) void flash_attn_mfma(
    const unsigned short* __restrict__ q_ws,
    const unsigned short* __restrict__ k_ws,
    const unsigned short* __restrict__ vt_ws,
    float* __restrict__ out,
    float* __restrict__ Op, float* __restrict__ l_p)
{
    __shared__ __align__(16) unsigned short KsU[TK * CH];     // 16 KB single
    __shared__ __align__(16) unsigned short VtU[2][CH * TK];  // 2 x 16 KB

    const int t    = threadIdx.x;
    const int w    = t >> 6;
    const int lane = t & 63;
    const int half = lane >> 5;
    const int l32  = lane & 31;
    const int jc   = blockIdx.y;
    const int b    = blockIdx.z;
    const int n0   = blockIdx.x * 128;

    constexpr int cbase = TILES / SPLIT;
    constexpr int crem  = TILES % SPLIT;
    const int myt = cbase + (jc < crem ? 1 : 0);
    const int t0  = jc * cbase + (jc < crem ? jc : crem);

    const unsigned short* kg = k_ws  + (size_t)b * NTOK * CH;
    const unsigned short* vg = vt_ws + (size_t)b * CH * NTOK;

    // Q B-frags: B[k=ch][n=q=l32], ch chunk = 16ks+8*half+j
    short8 qa[8];
    {
        const unsigned short* qrow =
            q_ws + ((size_t)b * NTOK + n0 + 32 * w + l32) * CH;
        #pragma unroll
        for (int ks = 0; ks < 8; ++ks)
            qa[ks] = *(const short8*)(qrow + ks * 16 + half * 8);
    }

    f32x16 Oa[4];  // O^T tiles, D[m=ch 32ct..][n=q]
    #pragma unroll
    for (int ct = 0; ct < 4; ++ct) Oa[ct] = (f32x16)(0.0f);
    float lsum = 0.f;

    const int krl = lane >> 4, ku = lane & 15;
    const int vcl = lane >> 3, vu = lane & 7;

    auto K_DMA = [&](int jj) {
        #pragma unroll
        for (int ci = 0; ci < 4; ++ci) {
            const int row = 16 * w + 4 * ci + krl;
            const int g   = ku ^ (row & 15);
            const unsigned short* src = kg + (size_t)(jj + row) * CH + g * 8;
            __builtin_amdgcn_global_load_lds(
                (const __attribute__((address_space(1))) void*)src,
                (__attribute__((address_space(3))) void*)&KsU[(16 * w + 4 * ci) * CH],
                16, 0, 0);
        }
    };
    auto V_DMA = [&](int buf, int jj) {
        #pragma unroll
        for (int ci = 0; ci < 4; ++ci) {
            const int c = 32 * w + 8 * ci + vcl;
            const int g = vu ^ (c & 7);
            const unsigned short* src = vg + (size_t)c * NTOK + jj + g * 8;
            __builtin_amdgcn_global_load_lds(
                (const __attribute__((address_space(1))) void*)src,
                (__attribute__((address_space(3))) void*)&VtU[buf][(32 * w + 8 * ci) * TK],
                16, 0, 0);
        }
    };

    K_DMA(t0 * TK);
    V_DMA(0, t0 * TK);

    for (int tt = 0; tt < myt; ++tt) {
        const int cur = tt & 1;
        asm volatile("s_waitcnt vmcnt(0)" ::: "memory");  // own K(t),V(t) landed
        __builtin_amdgcn_sched_barrier(0);
        __builtin_amdgcn_s_barrier();                     // B1: landed everywhere
        __builtin_amdgcn_sched_barrier(0);

        // --- S^T = K Q^T - MFIX : D[m=ktok][n=q] ; lane holds q=l32 ---
        // KsU base is compile-time -> addresses loop-invariant (LICM).
        f32x16 s[2];
        s[0] = (f32x16)(-MFIX);
        s[1] = (f32x16)(-MFIX);
        #pragma unroll
        for (int ks = 0; ks < 8; ++ks) {
            const int ph = (2 * ks + half) ^ (l32 & 15);
            const short8 kf0 = *(const short8*)&KsU[l32 * CH + ph * 8];
            const short8 kf1 = *(const short8*)&KsU[(32 + l32) * CH + ph * 8];
            s[0] = __builtin_amdgcn_mfma_f32_32x32x16_bf16(kf0, qa[ks], s[0], 0, 0, 0);
            s[1] = __builtin_amdgcn_mfma_f32_32x32x16_bf16(kf1, qa[ks], s[1], 0, 0, 0);
        }
        __builtin_amdgcn_sched_barrier(0);
        __builtin_amdgcn_s_barrier();                     // B1.5: K readers done
        __builtin_amdgcn_sched_barrier(0);
        if (tt + 1 < myt) {                               // uniform branch
            K_DMA((t0 + tt + 1) * TK);
            V_DMA(cur ^ 1, (t0 + tt + 1) * TK);
        }

        // --- P = exp2(S) in-register; pack to PV B-frags via cvt_pk+permlane ---
        short8 pb[4];  // B[k=16ks2+8h+j][n=q]
        #pragma unroll
        for (int kt = 0; kt < 2; ++kt) {
            float p[16];
            #pragma unroll
            for (int r = 0; r < 16; ++r) p[r] = exp2f(s[kt][r]);
            float a0 = 0.f, a1 = 0.f, a2 = 0.f, a3 = 0.f;
            #pragma unroll
            for (int r = 0; r < 4; ++r) {
                a0 += p[r]; a1 += p[4 + r]; a2 += p[8 + r]; a3 += p[12 + r];
            }
            lsum += (a0 + a1) + (a2 + a3);
            unsigned wd[8];
            #pragma unroll
            for (int i = 0; i < 8; ++i) wd[i] = cvt_pk_bf16(p[2 * i], p[2 * i + 1]);
            auto r02 = __builtin_amdgcn_permlane32_swap(wd[0], wd[2], false, false);
            auto r13 = __builtin_amdgcn_permlane32_swap(wd[1], wd[3], false, false);
            auto r46 = __builtin_amdgcn_permlane32_swap(wd[4], wd[6], false, false);
            auto r57 = __builtin_amdgcn_permlane32_swap(wd[5], wd[7], false, false);
            union { unsigned u[4]; short8 s8; } f0, f1;
            f0.u[0] = r02[0]; f0.u[1] = r13[0]; f0.u[2] = r02[1]; f0.u[3] = r13[1];
            f1.u[0] = r46[0]; f1.u[1] = r57[0]; f1.u[2] = r46[1]; f1.u[3] = r57[1];
            pb[2 * kt + 0] = f0.s8;
            pb[2 * kt + 1] = f1.s8;
        }

        // --- O^T += V^T P^T (reads VtU[cur]; next-tile DMAs write cur^1) ---
        const unsigned short* Vc = &VtU[cur][0];
        #pragma unroll
        for (int ks2 = 0; ks2 < 4; ++ks2) {
            #pragma unroll
            for (int ct = 0; ct < 4; ++ct) {
                const int ch = 32 * ct + l32;
                const int ph = (2 * ks2 + half) ^ (ch & 7);
                const short8 vf = *(const short8*)&Vc[ch * TK + ph * 8];
                Oa[ct] = __builtin_amdgcn_mfma_f32_32x32x16_bf16(vf, pb[ks2], Oa[ct], 0, 0, 0);
            }
        }
    }

    // --- epilogue: l lane-local; stores coalesced (lane = token) ---
    const float lt = lsum + __shfl_xor(lsum, 32);
    const int n = n0 + 32 * w + l32;

    if constexpr (SPLIT == 1) {
        const float inv = 1.0f / lt;
        #pragma unroll
        for (int ct = 0; ct < 4; ++ct) {
            #pragma unroll
            for (int r = 0; r < 16; ++r) {
                const int c = 32 * ct + (r & 3) + 8 * (r >> 2) + 4 * half;
                out[((size_t)b * CH + c) * NTOK + n] = Oa[ct][r] * inv;
            }
        }
    } else {
        const size_t chunk = (size_t)(b * SPLIT + jc);
        #pragma unroll
        for (int ct = 0; ct < 4; ++ct) {
            #pragma unroll
            for (int r = 0; r < 16; ++r) {
                const int c = 32 * ct + (r & 3) + 8 * (r >> 2) + 4 * half;
                Op[(chunk * CH + c) * NTOK + n] = Oa[ct][r];
            }
        }
        if (half == 0) l_p[chunk * NTOK + n] = lt;
    }
}

// ---------------- combine partials: Op layout [chunk][C][N], coalesced -----
template <int SPLIT>
__global__ __launch_bounds__(256) void combine_kernel(
    const float* __restrict__ Op, const float* __restrict__ l_p,
    float* __restrict__ out)
{
    const int b = blockIdx.y;
    const size_t idx = ((size_t)blockIdx.x * 256 + threadIdx.x) * 4;  // in C*N
    const int c = (int)(idx >> 12);           // / NTOK
    const int n = (int)(idx & (NTOK - 1));
    float4 acc = make_float4(0.f, 0.f, 0.f, 0.f);
    float4 den = make_float4(0.f, 0.f, 0.f, 0.f);
    #pragma unroll
    for (int j = 0; j < SPLIT; ++j) {
        const size_t chunk = (size_t)(b * SPLIT + j);
        const float4 o = *(const float4*)&Op[(chunk * CH + c) * NTOK + n];
        const float4 d = *(const float4*)&l_p[chunk * NTOK + n];
        acc.x += o.x; acc.y += o.y; acc.z += o.z; acc.w += o.w;
        den.x += d.x; den.y += d.y; den.z += d.z; den.w += d.w;
    }
    float4 r;
    r.x = acc.x / den.x; r.y = acc.y / den.y;
    r.z = acc.z / den.z; r.w = acc.w / den.w;
    *(float4*)&out[((size_t)b * CH * NTOK) + idx] = r;
}

extern "C" void kernel_launch(void* const* d_in, const int* in_sizes, int n_in,
                              void* d_out, int out_size, void* d_ws, size_t ws_size,
                              hipStream_t stream) {
    const float* x  = (const float*)d_in[0];
    const float* Wq = (const float*)d_in[1];
    const float* bq = (const float*)d_in[2];
    const float* Wk = (const float*)d_in[3];
    const float* bk = (const float*)d_in[4];
    const float* Wv = (const float*)d_in[5];
    const float* bv = (const float*)d_in[6];
    float* out = (float*)d_out;

    const size_t QKV = (size_t)BATCH * NTOK * CH;
    unsigned short* q_ws  = (unsigned short*)d_ws;
    unsigned short* k_ws  = q_ws + QKV;
    unsigned short* vt_ws = k_ws + QKV;
    float* Op = (float*)(vt_ws + QKV);

    const size_t baseBytes = 3 * QKV * 2;
    auto needBytes = [&](size_t S) {
        return baseBytes + S * BATCH * NTOK * (size_t)(CH * 4 + 4);
    };

    dim3 gp(NTOK / 64, BATCH, 3);
    proj_mfma_kernel<<<gp, 256, 0, stream>>>(x, Wq, Wk, Wv, bq, bk, bv,
                                             q_ws, k_ws, vt_ws);

    dim3 gc(CH * NTOK / 1024, BATCH);
    if (ws_size >= needBytes(6)) {
        float* l_p = Op + (size_t)6 * BATCH * NTOK * CH;
        dim3 ga(NTOK / 128, 6, BATCH);
        flash_attn_mfma<6><<<ga, 256, 0, stream>>>(q_ws, k_ws, vt_ws, out, Op, l_p);
        combine_kernel<6><<<gc, 256, 0, stream>>>(Op, l_p, out);
    } else if (ws_size >= needBytes(4)) {
        float* l_p = Op + (size_t)4 * BATCH * NTOK * CH;
        dim3 ga(NTOK / 128, 4, BATCH);
        flash_attn_mfma<4><<<ga, 256, 0, stream>>>(q_ws, k_ws, vt_ws, out, Op, l_p);
        combine_kernel<4><<<gc, 256, 0, stream>>>(Op, l_p, out);
    } else {
        dim3 ga(NTOK / 128, 1, BATCH);
        flash_attn_mfma<1><<<ga, 256, 0, stream>>>(q_ws, k_ws, vt_ws, out,
                                                   nullptr, nullptr);
    }
}

// Round 6
// 126.854 us; speedup vs baseline: 1.1250x; 1.1250x over previous
//
#include <hip/hip_runtime.h>
#include <hip/hip_bf16.h>

// B=4, C=128, H=W=64 -> N=4096. ALL I/O FP32.
// Round 11: proj W-in-LDS attack; flash reverted to proven R7 (51.3us).
//  Residual accounting across R1/R2/R9/R10: total-flash ~= 78us, insensitive
//  to stores/convert/combine => proj ~50us vs ~8us roofline. Unchanged-across-
//  variants suspect: per-thread W streaming (64x16B loads of a 64KB matrix
//  per thread from L2 at ~200cy with 1-3 blocks/CU). Fix: W staged to LDS
//  once per block (cooperative coalesced + cvt_pk + XOR swizzle), MFMA W-frags
//  read from LDS (conflict-free (4ks+quad)^c16 pattern). x staging packs via
//  cvt_pk. Scatter stores kept (R9: bounce ~= scatter). No convert kernel.

#define BATCH 4
#define CH    128
#define NTOK  4096
#define TK    64
#define SCALE 0.08838834764831845f   // 1/sqrt(128)
#define LOG2E 1.4426950408889634f
#define MFIX  16.0f                  // fixed softmax offset (log2 units)

typedef __attribute__((ext_vector_type(8)))  short short8;
typedef __attribute__((ext_vector_type(4)))  float f32x4;
typedef __attribute__((ext_vector_type(16))) float f32x16;

static __device__ __forceinline__ unsigned short f2bf(float f) {
    __hip_bfloat16 h = (__hip_bfloat16)f;
    return *(const unsigned short*)&h;
}

static __device__ __forceinline__ unsigned cvt_pk_bf16(float lo, float hi) {
    unsigned r;
    asm("v_cvt_pk_bf16_f32 %0, %1, %2" : "=v"(r) : "v"(lo), "v"(hi));
    return r;
}

static __device__ __forceinline__ short8 pack_bf16x8(float4 a, float4 b) {
    union { unsigned u[4]; short8 s8; } f;
    f.u[0] = cvt_pk_bf16(a.x, a.y);
    f.u[1] = cvt_pk_bf16(a.z, a.w);
    f.u[2] = cvt_pk_bf16(b.x, b.y);
    f.u[3] = cvt_pk_bf16(b.z, b.w);
    return f.s8;
}

// ---------------- MFMA QKV projection, z-split, W staged in LDS ------------
// grid (NTOK/64, BATCH, 3), 256 thr. Per block: its W (32KB bf16, swizzled)
// loaded cooperatively once; x tile (16KB bf16 transposed, swizzled).
__global__ __launch_bounds__(256) void proj_mfma_kernel(
    const float* __restrict__ x,
    const float* __restrict__ Wq, const float* __restrict__ Wk,
    const float* __restrict__ Wv,
    const float* __restrict__ bq, const float* __restrict__ bk,
    const float* __restrict__ bv,
    unsigned short* __restrict__ q_ws, unsigned short* __restrict__ k_ws,
    unsigned short* __restrict__ vt_ws)
{
    __shared__ __align__(16) unsigned short Wl[CH * CH];   // 32 KB, swizzled
    __shared__ __align__(16) unsigned short XsT[64 * CH];  // 16 KB, swizzled

    const int t    = threadIdx.x;
    const int w    = t >> 6;
    const int lane = t & 63;
    const int quad = lane >> 4;
    const int c16  = lane & 15;
    const int n0   = blockIdx.x * 64;
    const int b    = blockIdx.y;
    const int z    = blockIdx.z;          // 0=Q, 1=K, 2=V
    const float* xb = x + (size_t)b * CH * NTOK;
    const float* wm = (z == 0) ? Wq : (z == 1) ? Wk : Wv;

    // ---- cooperative W load: 2048 units of 8 floats; unit f -> row f>>4,
    //      u f&15, phys u^(row&15). Consecutive lanes = consecutive units
    //      (32B/lane segments, coalesced). ----
    #pragma unroll
    for (int i = 0; i < 8; ++i) {
        const int f   = i * 256 + t;
        const int row = f >> 4;
        const int u   = f & 15;
        const float* src = wm + f * 8;
        const float4 a = *(const float4*)src;
        const float4 c = *(const float4*)(src + 4);
        *(short8*)&Wl[row * CH + (u ^ (row & 15)) * 8] = pack_bf16x8(a, c);
    }

    {   // stage x tile transposed: wave w covers channels 32w..32w+31
        const int tok = lane;
        #pragma unroll
        for (int cc = 0; cc < 4; ++cc) {
            const int cb = 32 * w + 8 * cc;
            float xv[8];
            #pragma unroll
            for (int j = 0; j < 8; ++j)
                xv[j] = xb[(size_t)(cb + j) * NTOK + n0 + tok];
            union { unsigned u[4]; short8 s8; } pk;
            #pragma unroll
            for (int j = 0; j < 4; ++j)
                pk.u[j] = cvt_pk_bf16(xv[2 * j], xv[2 * j + 1]);
            const int phys = ((cb >> 3) ^ (tok & 15));
            *(short8*)&XsT[tok * CH + phys * 8] = pk.s8;
        }
    }
    __syncthreads();

    if (z < 2) {
        // ---- Q or K: out[n][c'] = sum_c x[n][c] W[c'][c] + b ----
        const float* bias = (z == 0) ? bq : bk;
        unsigned short* dst = (z == 0) ? q_ws : k_ws;
        const float mul = (z == 0) ? (SCALE * LOG2E) : 1.0f;

        short8 xa[4];
        #pragma unroll
        for (int ks = 0; ks < 4; ++ks)
            xa[ks] = *(const short8*)&XsT[(16 * w + c16) * CH + (((4 * ks + quad) ^ c16) << 3)];

        #pragma unroll
        for (int nt = 0; nt < 8; ++nt) {
            f32x4 a = (f32x4){0.f, 0.f, 0.f, 0.f};
            #pragma unroll
            for (int ks = 0; ks < 4; ++ks) {
                const short8 bf = *(const short8*)
                    &Wl[(16 * nt + c16) * CH + (((4 * ks + quad) ^ c16) << 3)];
                a = __builtin_amdgcn_mfma_f32_16x16x32_bf16(xa[ks], bf, a, 0, 0, 0);
            }
            const float bvv = bias[16 * nt + c16];
            #pragma unroll
            for (int r = 0; r < 4; ++r) {
                const int n = n0 + 16 * w + quad * 4 + r;
                dst[((size_t)b * NTOK + n) * CH + 16 * nt + c16] =
                    f2bf((a[r] + bvv) * mul);
            }
        }
    } else {
        // ---- V (transposed output vt[c][n]) ----
        #pragma unroll
        for (int nt = 0; nt < 4; ++nt) {
            short8 xbf[4];
            #pragma unroll
            for (int ks = 0; ks < 4; ++ks)
                xbf[ks] = *(const short8*)&XsT[(16 * nt + c16) * CH + (((4 * ks + quad) ^ c16) << 3)];
            #pragma unroll
            for (int mt = 0; mt < 2; ++mt) {
                const int crow16 = 16 * (2 * w + mt);
                f32x4 acc = (f32x4){0.f, 0.f, 0.f, 0.f};
                #pragma unroll
                for (int ks = 0; ks < 4; ++ks) {
                    const short8 wva = *(const short8*)
                        &Wl[(crow16 + c16) * CH + (((4 * ks + quad) ^ c16) << 3)];
                    acc = __builtin_amdgcn_mfma_f32_16x16x32_bf16(wva, xbf[ks], acc, 0, 0, 0);
                }
                #pragma unroll
                for (int r = 0; r < 4; ++r) {
                    const int crow = crow16 + quad * 4 + r;
                    vt_ws[((size_t)b * CH + crow) * NTOK + n0 + 16 * nt + c16] =
                        f2bf(acc[r] + bv[crow]);
                }
            }
        }
    }
}

// ---------------- split-KV MFMA flash attention (exact R7, proven 51.3us) --
template <int SPLIT>
__global__ __launch_bounds__(256, 2) void flash_attn_mfma(
    const unsigned short* __restrict__ q_ws,
    const unsigned short* __restrict__ k_ws,
    const unsigned short* __restrict__ vt_ws,
    float* __restrict__ out,
    float* __restrict__ Op, float* __restrict__ l_p)
{
    __shared__ __align__(16) unsigned short KsU[2][TK * CH];  // 2 x 16 KB
    __shared__ __align__(16) unsigned short VtU[2][CH * TK];  // 2 x 16 KB

    const int t    = threadIdx.x;
    const int w    = t >> 6;
    const int lane = t & 63;
    const int half = lane >> 5;
    const int l32  = lane & 31;
    const int jc   = blockIdx.y;
    const int b    = blockIdx.z;
    const int n0   = blockIdx.x * 128;
    const int jbeg = jc * (NTOK / SPLIT);
    constexpr int NT = (NTOK / SPLIT) / TK;

    const unsigned short* kg = k_ws  + (size_t)b * NTOK * CH;
    const unsigned short* vg = vt_ws + (size_t)b * CH * NTOK;

    // Q B-frags: B[k=ch][n=q=l32], ch chunk = 16ks+8*half+j
    short8 qa[8];
    {
        const unsigned short* qrow =
            q_ws + ((size_t)b * NTOK + n0 + 32 * w + l32) * CH;
        #pragma unroll
        for (int ks = 0; ks < 8; ++ks)
            qa[ks] = *(const short8*)(qrow + ks * 16 + half * 8);
    }

    f32x16 Oa[4];  // O^T tiles, D[m=ch 32ct..][n=q]
    #pragma unroll
    for (int ct = 0; ct < 4; ++ct) Oa[ct] = (f32x16)(0.0f);
    float lsum = 0.f;

    const int krl = lane >> 4, ku = lane & 15;
    const int vcl = lane >> 3, vu = lane & 7;

    auto STAGE = [&](int buf, int jj) {
        // K rows 16w..16w+15 (XOR-swizzled source, linear LDS dest)
        #pragma unroll
        for (int ci = 0; ci < 4; ++ci) {
            const int row = 16 * w + 4 * ci + krl;
            const int g   = ku ^ (row & 15);
            const unsigned short* src = kg + (size_t)(jj + row) * CH + g * 8;
            __builtin_amdgcn_global_load_lds(
                (const __attribute__((address_space(1))) void*)src,
                (__attribute__((address_space(3))) void*)&KsU[buf][(16 * w + 4 * ci) * CH],
                16, 0, 0);
        }
        // V^T channel rows 32w..32w+31
        #pragma unroll
        for (int ci = 0; ci < 4; ++ci) {
            const int c = 32 * w + 8 * ci + vcl;
            const int g = vu ^ (c & 7);
            const unsigned short* src = vg + (size_t)c * NTOK + jj + g * 8;
            __builtin_amdgcn_global_load_lds(
                (const __attribute__((address_space(1))) void*)src,
                (__attribute__((address_space(3))) void*)&VtU[buf][(32 * w + 8 * ci) * TK],
                16, 0, 0);
        }
    };

    STAGE(0, jbeg);   // 8 loads/wave in flight

    int j0 = jbeg;
    for (int tt = 0; tt < NT; ++tt, j0 += TK) {
        const int cur = tt & 1;
        if (tt + 1 < NT) {
            STAGE(cur ^ 1, j0 + TK);                         // prefetch next
            asm volatile("s_waitcnt vmcnt(8)" ::: "memory"); // own cur loads done
        } else {
            asm volatile("s_waitcnt vmcnt(0)" ::: "memory");
        }
        __builtin_amdgcn_sched_barrier(0);
        __builtin_amdgcn_s_barrier();                        // all waves' cur landed
        __builtin_amdgcn_sched_barrier(0);

        const unsigned short* Kc = &KsU[cur][0];
        const unsigned short* Vc = &VtU[cur][0];

        // --- S^T = K Q^T - MFIX : D[m=ktok][n=q] ; lane holds q=l32 ---
        f32x16 s[2];
        s[0] = (f32x16)(-MFIX);
        s[1] = (f32x16)(-MFIX);
        #pragma unroll
        for (int ks = 0; ks < 8; ++ks) {
            const int ph = (2 * ks + half) ^ (l32 & 15);
            const short8 kf0 = *(const short8*)&Kc[l32 * CH + ph * 8];
            const short8 kf1 = *(const short8*)&Kc[(32 + l32) * CH + ph * 8];
            s[0] = __builtin_amdgcn_mfma_f32_32x32x16_bf16(kf0, qa[ks], s[0], 0, 0, 0);
            s[1] = __builtin_amdgcn_mfma_f32_32x32x16_bf16(kf1, qa[ks], s[1], 0, 0, 0);
        }

        // --- P = exp2(S) in-register; pack to PV B-frags via cvt_pk+permlane ---
        short8 pb[4];  // B[k=16ks2+8h+j][n=q]
        #pragma unroll
        for (int kt = 0; kt < 2; ++kt) {
            float p[16];
            #pragma unroll
            for (int r = 0; r < 16; ++r) p[r] = exp2f(s[kt][r]);
            float a0 = 0.f, a1 = 0.f, a2 = 0.f, a3 = 0.f;
            #pragma unroll
            for (int r = 0; r < 4; ++r) {
                a0 += p[r]; a1 += p[4 + r]; a2 += p[8 + r]; a3 += p[12 + r];
            }
            lsum += (a0 + a1) + (a2 + a3);
            unsigned wd[8];
            #pragma unroll
            for (int i = 0; i < 8; ++i) wd[i] = cvt_pk_bf16(p[2 * i], p[2 * i + 1]);
            auto r02 = __builtin_amdgcn_permlane32_swap(wd[0], wd[2], false, false);
            auto r13 = __builtin_amdgcn_permlane32_swap(wd[1], wd[3], false, false);
            auto r46 = __builtin_amdgcn_permlane32_swap(wd[4], wd[6], false, false);
            auto r57 = __builtin_amdgcn_permlane32_swap(wd[5], wd[7], false, false);
            union { unsigned u[4]; short8 s8; } f0, f1;
            f0.u[0] = r02[0]; f0.u[1] = r13[0]; f0.u[2] = r02[1]; f0.u[3] = r13[1];
            f1.u[0] = r46[0]; f1.u[1] = r57[0]; f1.u[2] = r46[1]; f1.u[3] = r57[1];
            pb[2 * kt + 0] = f0.s8;
            pb[2 * kt + 1] = f1.s8;
        }

        // --- O^T += V^T P^T ---
        #pragma unroll
        for (int ks2 = 0; ks2 < 4; ++ks2) {
            #pragma unroll
            for (int ct = 0; ct < 4; ++ct) {
                const int ch = 32 * ct + l32;
                const int ph = (2 * ks2 + half) ^ (ch & 7);
                const short8 vf = *(const short8*)&Vc[ch * TK + ph * 8];
                Oa[ct] = __builtin_amdgcn_mfma_f32_32x32x16_bf16(vf, pb[ks2], Oa[ct], 0, 0, 0);
            }
        }
        __builtin_amdgcn_sched_barrier(0);
        __builtin_amdgcn_s_barrier();   // all waves done reading cur before re-stage
        __builtin_amdgcn_sched_barrier(0);
    }

    // --- epilogue: l lane-local; stores coalesced (lane = token) ---
    const float lt = lsum + __shfl_xor(lsum, 32);
    const int n = n0 + 32 * w + l32;

    if constexpr (SPLIT == 1) {
        const float inv = 1.0f / lt;
        #pragma unroll
        for (int ct = 0; ct < 4; ++ct) {
            #pragma unroll
            for (int r = 0; r < 16; ++r) {
                const int c = 32 * ct + (r & 3) + 8 * (r >> 2) + 4 * half;
                out[((size_t)b * CH + c) * NTOK + n] = Oa[ct][r] * inv;
            }
        }
    } else {
        const size_t chunk = (size_t)(b * SPLIT + jc);
        #pragma unroll
        for (int ct = 0; ct < 4; ++ct) {
            #pragma unroll
            for (int r = 0; r < 16; ++r) {
                const int c = 32 * ct + (r & 3) + 8 * (r >> 2) + 4 * half;
                Op[(chunk * CH + c) * NTOK + n] = Oa[ct][r];
            }
        }
        if (half == 0) l_p[chunk * NTOK + n] = lt;
    }
}

// ---------------- combine partials: Op layout [chunk][C][N], coalesced -----
template <int SPLIT>
__global__ __launch_bounds__(256) void combine_kernel(
    const float* __restrict__ Op, const float* __restrict__ l_p,
    float* __restrict__ out)
{
    const int b = blockIdx.y;
    const size_t idx = ((size_t)blockIdx.x * 256 + threadIdx.x) * 4;  // in C*N
    const int c = (int)(idx >> 12);           // / NTOK
    const int n = (int)(idx & (NTOK - 1));
    float4 acc = make_float4(0.f, 0.f, 0.f, 0.f);
    float4 den = make_float4(0.f, 0.f, 0.f, 0.f);
    #pragma unroll
    for (int j = 0; j < SPLIT; ++j) {
        const size_t chunk = (size_t)(b * SPLIT + j);
        const float4 o = *(const float4*)&Op[(chunk * CH + c) * NTOK + n];
        const float4 d = *(const float4*)&l_p[chunk * NTOK + n];
        acc.x += o.x; acc.y += o.y; acc.z += o.z; acc.w += o.w;
        den.x += d.x; den.y += d.y; den.z += d.z; den.w += d.w;
    }
    float4 r;
    r.x = acc.x / den.x; r.y = acc.y / den.y;
    r.z = acc.z / den.z; r.w = acc.w / den.w;
    *(float4*)&out[((size_t)b * CH * NTOK) + idx] = r;
}

extern "C" void kernel_launch(void* const* d_in, const int* in_sizes, int n_in,
                              void* d_out, int out_size, void* d_ws, size_t ws_size,
                              hipStream_t stream) {
    const float* x  = (const float*)d_in[0];
    const float* Wq = (const float*)d_in[1];
    const float* bq = (const float*)d_in[2];
    const float* Wk = (const float*)d_in[3];
    const float* bk = (const float*)d_in[4];
    const float* Wv = (const float*)d_in[5];
    const float* bv = (const float*)d_in[6];
    float* out = (float*)d_out;

    const size_t QKV = (size_t)BATCH * NTOK * CH;
    unsigned short* q_ws  = (unsigned short*)d_ws;
    unsigned short* k_ws  = q_ws + QKV;
    unsigned short* vt_ws = k_ws + QKV;
    float* Op = (float*)(vt_ws + QKV);

    const size_t baseBytes = 3 * QKV * 2;
    auto needBytes = [&](size_t S) {
        return baseBytes + S * BATCH * NTOK * (size_t)(CH * 4 + 4);
    };

    dim3 gp(NTOK / 64, BATCH, 3);
    proj_mfma_kernel<<<gp, 256, 0, stream>>>(x, Wq, Wk, Wv, bq, bk, bv,
                                             q_ws, k_ws, vt_ws);

    dim3 gc(CH * NTOK / 1024, BATCH);
    if (ws_size >= needBytes(4)) {
        float* l_p = Op + (size_t)4 * BATCH * NTOK * CH;
        dim3 ga(NTOK / 128, 4, BATCH);
        flash_attn_mfma<4><<<ga, 256, 0, stream>>>(q_ws, k_ws, vt_ws, out, Op, l_p);
        combine_kernel<4><<<gc, 256, 0, stream>>>(Op, l_p, out);
    } else if (ws_size >= needBytes(2)) {
        float* l_p = Op + (size_t)2 * BATCH * NTOK * CH;
        dim3 ga(NTOK / 128, 2, BATCH);
        flash_attn_mfma<2><<<ga, 256, 0, stream>>>(q_ws, k_ws, vt_ws, out, Op, l_p);
        combine_kernel<2><<<gc, 256, 0, stream>>>(Op, l_p, out);
    } else {
        dim3 ga(NTOK / 128, 1, BATCH);
        flash_attn_mfma<1><<<ga, 256, 0, stream>>>(q_ws, k_ws, vt_ws, out,
                                                   nullptr, nullptr);
    }
}